// Round 16
// baseline (283.227 us; speedup 1.0000x reference)
//
#include <hip/hip_runtime.h>
#include <hip/hip_bf16.h>

typedef __attribute__((ext_vector_type(8))) short short8;
typedef __attribute__((ext_vector_type(4))) float f32x4;
typedef __attribute__((ext_vector_type(16))) float f32x16;
typedef __attribute__((ext_vector_type(4))) unsigned short ushort4v;
typedef __attribute__((ext_vector_type(8))) unsigned short ushort8v;
typedef __attribute__((ext_vector_type(4))) unsigned int uint4v;

#define S_LEN 2048
#define DMODEL 1024
#define NHEAD 16
#define DHEAD 64
#define BATCH 4
#define NEGBIG (-1.0e30f)
#define LOG2E 1.4426950408889634f

__device__ __forceinline__ unsigned short f2bf(float f) {
  unsigned int u = __builtin_bit_cast(unsigned int, f);
  u += 0x7fffu + ((u >> 16) & 1u);
  return (unsigned short)(u >> 16);
}

// compiler-sanctioned packed f32x2 -> bf16x2 (lo -> bits[15:0])
__device__ __forceinline__ unsigned int pk2bf(float lo, float hi) {
  __hip_bfloat162 t = __float22bfloat162_rn(make_float2(lo, hi));
  unsigned int r;
  __builtin_memcpy(&r, &t, 4);
  return r;
}

__device__ __forceinline__ void gload16(const void* src, void* lds_dst) {
  __builtin_amdgcn_global_load_lds(
      (const __attribute__((address_space(1))) unsigned int*)src,
      (__attribute__((address_space(3))) unsigned int*)lds_dst, 16, 0, 0);
}

// ---------------- fp32 -> bf16 conversion (weights only) ----------------
__global__ __launch_bounds__(256) void cvt4_kernel(
    const float* __restrict__ i0, const float* __restrict__ i1,
    const float* __restrict__ i2, const float* __restrict__ i3,
    unsigned short* __restrict__ o0, unsigned short* __restrict__ o1,
    unsigned short* __restrict__ o2, unsigned short* __restrict__ o3, int n) {
  const float* in = (blockIdx.y == 0) ? i0 : (blockIdx.y == 1) ? i1 : (blockIdx.y == 2) ? i2 : i3;
  unsigned short* out = (blockIdx.y == 0) ? o0 : (blockIdx.y == 1) ? o1 : (blockIdx.y == 2) ? o2 : o3;
  int idx = blockIdx.x * blockDim.x + threadIdx.x;
  int stride = gridDim.x * blockDim.x;
  for (int j = idx * 8; j < n; j += stride * 8) {
    float4 a = *(const float4*)(in + j);
    float4 b = *(const float4*)(in + j + 4);
    ushort8v r;
    r[0] = f2bf(a.x); r[1] = f2bf(a.y); r[2] = f2bf(a.z); r[3] = f2bf(a.w);
    r[4] = f2bf(b.x); r[5] = f2bf(b.y); r[6] = f2bf(b.z); r[7] = f2bf(b.w);
    *(ushort8v*)(out + j) = r;
  }
}

// ------------- fused QKV GEMM: C = (A_f32[M][K] * W_bf16[N][K]^T + b) * osc -
// Reg-staged A (r13 proven); B double-buffered in LDS with EARLY issue:
// {issue areg(k+1), B(k+1)->buf^1} -> MFMA(A, B[cur]) -> lgkm-barrier ->
// cvt/ds_write A(k+1) -> __syncthreads.  The bottom vmcnt(0) drain hits
// B-gloads that are ~600cy old (MFMA+cvt elapsed) -> near-free.
__global__ __launch_bounds__(256) void qkv_gemm_kernel(
    const float* __restrict__ Aq, const float* __restrict__ Ak, const float* __restrict__ Av,
    const unsigned short* __restrict__ Wq, const unsigned short* __restrict__ Wk,
    const unsigned short* __restrict__ Wv,
    const float* __restrict__ bq, const float* __restrict__ bk, const float* __restrict__ bv,
    unsigned short* __restrict__ oq, unsigned short* __restrict__ ok,
    unsigned short* __restrict__ ov) {
  const int z = blockIdx.z;
  const float* A = (z == 0) ? Aq : (z == 1) ? Ak : Av;
  const unsigned short* W = (z == 0) ? Wq : (z == 1) ? Wk : Wv;
  const float* bias = (z == 0) ? bq : (z == 1) ? bk : bv;
  unsigned short* out = (z == 0) ? oq : (z == 1) ? ok : ov;
  const float oscale = (z == 0) ? 0.125f * LOG2E : 1.0f;
  const int N = DMODEL, K = DMODEL;

  __shared__ char lds[49152];  // A bf16 [0,16K) | B dbuf [16K,48K)
  const int tid = threadIdx.x;
  const int lane = tid & 63;
  const int wv = tid >> 6;
  const int wr = wv >> 1, wc = wv & 1;
  const int l16 = lane & 15, lg = lane >> 4;

  const int nbx = N >> 7;  // 8
  const int swz = (blockIdx.x & 7) * ((int)gridDim.x >> 3) + (blockIdx.x >> 3);
  const int tm = swz / nbx, tn = swz % nbx;

  const char* Wb = (const char*)W;

  const int arow[4] = {(tid >> 3), 32 + (tid >> 3), 64 + (tid >> 3), 96 + (tid >> 3)};
  const int aslot = tid & 7;

  float4 areg[4][2];

  auto loadA = [&](int k0) {
#pragma unroll
    for (int j = 0; j < 4; ++j) {
      const float* ap = A + (size_t)(tm * 128 + arow[j]) * K + k0 + aslot * 8;
      areg[j][0] = *(const float4*)ap;
      areg[j][1] = *(const float4*)(ap + 4);
    }
  };
  auto stageB = [&](int k0, int buf) {
#pragma unroll
    for (int i = 0; i < 4; ++i) {
      int ch = wv * 4 + i;
      int r = ch * 8 + (lane >> 3);
      int cb = ((lane & 7) * 16) ^ ((r & 7) << 4);
      gload16(Wb + ((size_t)(tn * 128 + r) * K + k0) * 2 + cb,
              lds + 16384 + buf * 16384 + ch * 1024);
    }
  };
  auto cvtWriteA = [&]() {
#pragma unroll
    for (int j = 0; j < 4; ++j) {
      uint4v w4;
      w4[0] = pk2bf(areg[j][0].x, areg[j][0].y);
      w4[1] = pk2bf(areg[j][0].z, areg[j][0].w);
      w4[2] = pk2bf(areg[j][1].x, areg[j][1].y);
      w4[3] = pk2bf(areg[j][1].z, areg[j][1].w);
      int r = arow[j];
      *(uint4v*)(lds + r * 128 + ((aslot * 16) ^ ((r & 7) << 4))) = w4;
    }
  };

  f32x4 acc[4][4] = {};

  // prologue: areg(0) first (oldest vmcnt), then B(0) -> buf0
  loadA(0);
  stageB(0, 0);
  cvtWriteA();          // compiler waits vmcnt(4): areg done, B(0) in flight
  __syncthreads();      // drains B(0) (pays one latency, once)

  int cur = 0;
  for (int k0 = 0; k0 < K; k0 += 64) {
    const bool more = (k0 + 64 < K);
    if (more) {
      loadA(k0 + 64);        // areg first -> older than B in vmcnt order
      stageB(k0 + 64, cur ^ 1);
    }
    // MFMA phase: A from [0,16K), B from buf cur
    const char* Bb = lds + 16384 + cur * 16384;
#pragma unroll
    for (int ks = 0; ks < 2; ++ks) {
      const int cbase = (ks * 32 + lg * 8) * 2;
      short8 af[4], bfr[4];
#pragma unroll
      for (int m = 0; m < 4; ++m) {
        int r = wr * 64 + m * 16 + l16;
        af[m] = *(const short8*)(lds + r * 128 + (cbase ^ ((r & 7) << 4)));
      }
#pragma unroll
      for (int n = 0; n < 4; ++n) {
        int r = wc * 64 + n * 16 + l16;
        bfr[n] = *(const short8*)(Bb + r * 128 + (cbase ^ ((r & 7) << 4)));
      }
#pragma unroll
      for (int m = 0; m < 4; ++m)
#pragma unroll
        for (int n = 0; n < 4; ++n)
          acc[m][n] = __builtin_amdgcn_mfma_f32_16x16x32_bf16(af[m], bfr[n], acc[m][n], 0, 0, 0);
    }
    if (more) {
      // A ds_reads retired in all waves -> safe to overwrite A buffer
      asm volatile("s_waitcnt lgkmcnt(0)" ::: "memory");
      __builtin_amdgcn_s_barrier();
      asm volatile("" ::: "memory");
      cvtWriteA();        // waits vmcnt(4): areg(k+1) done, B(k+1) in flight
      __syncthreads();    // drains B(k+1): issued ~600cy ago -> near-free
    }
    cur ^= 1;
  }

  // epilogue
#pragma unroll
  for (int n = 0; n < 4; ++n) {
    int gn = tn * 128 + wc * 64 + n * 16 + l16;
    float bv2 = bias[gn];
    int h = gn >> 6, dh = gn & 63;
#pragma unroll
    for (int m = 0; m < 4; ++m) {
      int gm0 = tm * 128 + wr * 64 + m * 16 + lg * 4;
      f32x4 a = acc[m][n];
      if (z < 2) {
#pragma unroll
        for (int rr = 0; rr < 4; ++rr) {
          int gm = gm0 + rr;
          int b = gm >> 11, s = gm & 2047;
          out[(((size_t)b * NHEAD + h) * S_LEN + s) * DHEAD + dh] = f2bf((a[rr] + bv2) * oscale);
        }
      } else {
        int b = gm0 >> 11, s0 = gm0 & 2047;
        ushort4v pk;
        pk[0] = f2bf(a[0] + bv2); pk[1] = f2bf(a[1] + bv2);
        pk[2] = f2bf(a[2] + bv2); pk[3] = f2bf(a[3] + bv2);
        *(ushort4v*)(out + (((size_t)b * NHEAD + h) * DHEAD + dh) * S_LEN + s0) = pk;
      }
    }
  }
}

// ---------------- output-projection GEMM (bf16 A, fp32 out) ----------------
__global__ __launch_bounds__(256) void gemm_o_kernel(
    const unsigned short* __restrict__ A, const unsigned short* __restrict__ W,
    const float* __restrict__ bias, float* __restrict__ outp, int M, int N, int K) {
  __shared__ char lds[32768];
  const int tid = threadIdx.x;
  const int lane = tid & 63;
  const int wv = tid >> 6;
  const int wr = wv >> 1, wc = wv & 1;
  const int l16 = lane & 15, lg = lane >> 4;

  const int nbx = N >> 7;
  const int nwg = gridDim.x;
  const int swz = (blockIdx.x & 7) * (nwg >> 3) + (blockIdx.x >> 3);
  const int tm = swz / nbx, tn = swz % nbx;

  const char* Ab = (const char*)A;
  const char* Wb = (const char*)W;

  f32x4 acc[4][4] = {};

  for (int k0 = 0; k0 < K; k0 += 64) {
#pragma unroll
    for (int i = 0; i < 8; ++i) {
      int ch = wv * 8 + i;
      int chl = ch & 15;
      int r = chl * 8 + (lane >> 3);
      int cb = ((lane & 7) * 16) ^ ((r & 7) << 4);
      const char* src = (ch < 16)
          ? Ab + ((size_t)(tm * 128 + r) * K + k0) * 2 + cb
          : Wb + ((size_t)(tn * 128 + r) * K + k0) * 2 + cb;
      gload16(src, lds + ch * 1024);
    }
    __syncthreads();
#pragma unroll
    for (int ks = 0; ks < 2; ++ks) {
      const int cbase = (ks * 32 + lg * 8) * 2;
      short8 af[4], bfr[4];
#pragma unroll
      for (int m = 0; m < 4; ++m) {
        int r = wr * 64 + m * 16 + l16;
        af[m] = *(const short8*)(lds + r * 128 + (cbase ^ ((r & 7) << 4)));
      }
#pragma unroll
      for (int n = 0; n < 4; ++n) {
        int r = wc * 64 + n * 16 + l16;
        bfr[n] = *(const short8*)(lds + 16384 + r * 128 + (cbase ^ ((r & 7) << 4)));
      }
#pragma unroll
      for (int m = 0; m < 4; ++m)
#pragma unroll
        for (int n = 0; n < 4; ++n)
          acc[m][n] = __builtin_amdgcn_mfma_f32_16x16x32_bf16(af[m], bfr[n], acc[m][n], 0, 0, 0);
    }
    __syncthreads();
  }

#pragma unroll
  for (int n = 0; n < 4; ++n) {
    int gn = tn * 128 + wc * 64 + n * 16 + l16;
    float bv = bias[gn];
#pragma unroll
    for (int m = 0; m < 4; ++m) {
      int gm0 = tm * 128 + wr * 64 + m * 16 + lg * 4;
      f32x4 a = acc[m][n];
#pragma unroll
      for (int rr = 0; rr < 4; ++rr)
        outp[(size_t)(gm0 + rr) * N + gn] = a[rr] + bv;
    }
  }
}

// ---------------- causal flash attention, 4-wave 32x32 swapped-QK ----------
// qh (pre-scaled by log2e/8), kh: [B,H,S,DH] bf16   vt: [B,H,DH,S] bf16
// aout: [B,S,D] bf16.  exp2-domain softmax; defer-max threshold 8.
// QBLK=128 unpaired; grid(64 bh, 16 qb) heavy-first; dbuf LDS.
// Packed-API P-pack; proven shfl_xor exchange; T5 setprio around MFMA.
__global__ __launch_bounds__(256) void attn_kernel(
    const unsigned short* __restrict__ qh, const unsigned short* __restrict__ kh,
    const unsigned short* __restrict__ vt, unsigned short* __restrict__ aout) {
  __shared__ char lds[32768];  // 2 x (K 8KB | Vt 8KB)
  const int tid = threadIdx.x;
  const int lane = tid & 63;
  const int w = tid >> 6;     // 0..3
  const int l31 = lane & 31;
  const int l5 = lane >> 5;   // 0/1
  const int bh = blockIdx.x;
  const int b = bh >> 4, h = bh & 15;

  const char* kbase = (const char*)(kh + (size_t)bh * S_LEN * DHEAD);
  const char* vbase = (const char*)(vt + (size_t)bh * S_LEN * DHEAD);
  const unsigned short* qbase = qh + (size_t)bh * S_LEN * DHEAD;

  const int la = lane >> 3, lb = lane & 7;

  const int qb = 15 - (int)blockIdx.y;  // heavy q-blocks dispatched first
  const int q0 = qb * 128;
  const int wq0 = q0 + w * 32;
  const int qg = wq0 + l31;
  const int nt = qb * 2 + 2;

  short8 qf[4];
#pragma unroll
  for (int f = 0; f < 4; ++f)
    qf[f] = *(const short8*)(qbase + (size_t)qg * DHEAD + f * 16 + l5 * 8);

  f32x16 oa[2] = {};
  float mrun = NEGBIG, lr = 0.f;

  // prologue: stage tile 0 into buf0
#pragma unroll
  for (int i = 0; i < 2; ++i) {
    int ch = w * 2 + i;
    int r = ch * 8 + la;
    int cb = (lb * 16) ^ ((r & 7) << 4);
    gload16(kbase + (size_t)r * 128 + cb, lds + ch * 1024 + lane * 16);
    gload16(vbase + (size_t)r * 4096 + cb, lds + 8192 + ch * 1024 + lane * 16);
  }
  __syncthreads();
  int cur = 0;

  for (int t = 0; t < nt; ++t) {
    const int kv0 = t * 64;
    if (t + 1 < nt) {
      char* nb = lds + (cur ^ 1) * 16384;
#pragma unroll
      for (int i = 0; i < 2; ++i) {
        int ch = w * 2 + i;
        int r = ch * 8 + la;
        int cb = (lb * 16) ^ ((r & 7) << 4);
        gload16(kbase + (size_t)(kv0 + 64 + r) * 128 + cb, nb + ch * 1024 + lane * 16);
        gload16(vbase + (size_t)r * 4096 + (size_t)(kv0 + 64) * 2 + cb,
                nb + 8192 + ch * 1024 + lane * 16);
      }
    }
    if (kv0 <= wq0 + 31) {
      const char* ldk = lds + cur * 16384;
      const char* ldv = ldk + 8192;

      // QK^T swapped: sa = K * Q^T  -> lane holds S[k][q=l31], 32 k's
      f32x16 sa[2] = {};
      __builtin_amdgcn_s_setprio(1);
#pragma unroll
      for (int kb2 = 0; kb2 < 2; ++kb2) {
        const int kr = kb2 * 32 + l31;
        const char* rowp = ldk + kr * 128;
        const int sw = (kr & 7) << 4;
#pragma unroll
        for (int f = 0; f < 4; ++f) {
          short8 kf = *(const short8*)(rowp + ((f * 32 + l5 * 16) ^ sw));
          sa[kb2] = __builtin_amdgcn_mfma_f32_32x32x16_bf16(kf, qf[f], sa[kb2], 0, 0, 0);
        }
      }
      __builtin_amdgcn_s_setprio(0);

      // causal mask (finite sentinel)
      if (kv0 + 63 > wq0) {
#pragma unroll
        for (int kb2 = 0; kb2 < 2; ++kb2)
#pragma unroll
          for (int r = 0; r < 16; ++r) {
            int kgl = kv0 + kb2 * 32 + (r & 3) + 8 * (r >> 2) + 4 * l5;
            if (kgl > qg) sa[kb2][r] = NEGBIG;
          }
      }

      // tile max (in-lane + one cross-half exchange)
      float pm = sa[0][0];
#pragma unroll
      for (int kb2 = 0; kb2 < 2; ++kb2)
#pragma unroll
        for (int r = 0; r < 16; ++r) pm = fmaxf(pm, sa[kb2][r]);
      pm = fmaxf(pm, __shfl_xor(pm, 32));

      // defer-max: rescale only when max grows beyond 2^8
      if (!__all(pm <= mrun + 8.f)) {
        float mN = fmaxf(mrun, pm);
        float sc = __builtin_amdgcn_exp2f(mrun - mN);
        mrun = mN;
        lr *= sc;
        oa[0] *= sc;
        oa[1] *= sc;
      }

      // exp2 + packed-API bf16 pack + cross-half exchange -> P^T B-fragments
      float rs = 0.f;
      short8 pfrag[4];
#pragma unroll
      for (int kb2 = 0; kb2 < 2; ++kb2) {
        unsigned int wpk[8];
#pragma unroll
        for (int i = 0; i < 8; ++i) {
          float p0 = __builtin_amdgcn_exp2f(sa[kb2][2 * i] - mrun);
          float p1 = __builtin_amdgcn_exp2f(sa[kb2][2 * i + 1] - mrun);
          rs += p0 + p1;
          wpk[i] = pk2bf(p0, p1);
        }
#pragma unroll
        for (int g = 0; g < 2; ++g) {
          unsigned int o0 = l5 ? wpk[4 * g + 2] : wpk[4 * g];
          unsigned int o1 = l5 ? wpk[4 * g + 3] : wpk[4 * g + 1];
          unsigned int s0 = l5 ? wpk[4 * g] : wpk[4 * g + 2];
          unsigned int s1 = l5 ? wpk[4 * g + 1] : wpk[4 * g + 3];
          unsigned int r0 = (unsigned int)__shfl_xor((int)s0, 32);
          unsigned int r1 = (unsigned int)__shfl_xor((int)s1, 32);
          uint4v fw;
          fw[0] = l5 ? r0 : o0;
          fw[1] = l5 ? r1 : o1;
          fw[2] = l5 ? o0 : r0;
          fw[3] = l5 ? o1 : r1;
          pfrag[kb2 * 2 + g] = __builtin_bit_cast(short8, fw);
        }
      }
      rs += __shfl_xor(rs, 32);
      lr += rs;

      // PV swapped: O^T += V^T * P^T
      __builtin_amdgcn_s_setprio(1);
#pragma unroll
      for (int db = 0; db < 2; ++db) {
        const int vr = db * 32 + l31;
        const char* rowp = ldv + vr * 128;
        const int sw = (vr & 7) << 4;
#pragma unroll
        for (int f = 0; f < 4; ++f) {
          short8 vf = *(const short8*)(rowp + ((f * 32 + l5 * 16) ^ sw));
          oa[db] = __builtin_amdgcn_mfma_f32_32x32x16_bf16(vf, pfrag[f], oa[db], 0, 0, 0);
        }
      }
      __builtin_amdgcn_s_setprio(0);
    }
    __syncthreads();
    cur ^= 1;
  }

  // epilogue: O^T / l  -> aout[b, q, h*64+dh]
  float rl = 1.0f / lr;
  unsigned short* obase = aout + ((size_t)(b * S_LEN + qg)) * DMODEL + h * DHEAD;
#pragma unroll
  for (int db = 0; db < 2; ++db)
#pragma unroll
    for (int rq = 0; rq < 4; ++rq) {
      ushort4v pk;
#pragma unroll
      for (int j = 0; j < 4; ++j)
        pk[j] = f2bf(oa[db][rq * 4 + j] * rl);
      *(ushort4v*)(obase + db * 32 + 8 * rq + 4 * l5) = pk;
    }
}

extern "C" void kernel_launch(void* const* d_in, const int* in_sizes, int n_in,
                              void* d_out, int out_size, void* d_ws, size_t ws_size,
                              hipStream_t stream) {
  (void)in_sizes; (void)n_in; (void)out_size; (void)ws_size;
  const float* q  = (const float*)d_in[0];
  const float* k  = (const float*)d_in[1];
  const float* v  = (const float*)d_in[2];
  const float* wq = (const float*)d_in[4];
  const float* bq = (const float*)d_in[5];
  const float* wk = (const float*)d_in[6];
  const float* bk = (const float*)d_in[7];
  const float* wv = (const float*)d_in[8];
  const float* bv = (const float*)d_in[9];
  const float* wo = (const float*)d_in[10];
  const float* bo = (const float*)d_in[11];

  const size_t NACT = (size_t)BATCH * S_LEN * DMODEL;
  const size_t NW = (size_t)DMODEL * DMODEL;
  unsigned short* wqb = (unsigned short*)d_ws;
  unsigned short* wkb = wqb + NW;
  unsigned short* wvb = wkb + NW;
  unsigned short* wob = wvb + NW;
  unsigned short* qhb = wob + NW;
  unsigned short* khb = qhb + NACT;
  unsigned short* vtb = khb + NACT;
  unsigned short* aout = vtb + NACT;

  dim3 blk(256);
  cvt4_kernel<<<dim3(512, 4), blk, 0, stream>>>(wq, wk, wv, wo, wqb, wkb, wvb, wob, (int)NW);

  const int M = BATCH * S_LEN, N = DMODEL, K = DMODEL;
  const int grid = (M / 128) * (N / 128);  // 512
  qkv_gemm_kernel<<<dim3(grid, 1, 3), blk, 0, stream>>>(
      q, k, v, wqb, wkb, wvb, bq, bk, bv, qhb, khb, vtb);

  attn_kernel<<<dim3(64, 16), blk, 0, stream>>>(qhb, khb, vtb, aout);

  gemm_o_kernel<<<grid, blk, 0, stream>>>(aout, wob, bo, (float*)d_out, M, N, K);
}

// Round 17
// 179.880 us; speedup vs baseline: 1.5745x; 1.5745x over previous
//
#include <hip/hip_runtime.h>
#include <hip/hip_bf16.h>

typedef __attribute__((ext_vector_type(8))) short short8;
typedef __attribute__((ext_vector_type(4))) float f32x4;
typedef __attribute__((ext_vector_type(16))) float f32x16;
typedef __attribute__((ext_vector_type(4))) unsigned short ushort4v;
typedef __attribute__((ext_vector_type(8))) unsigned short ushort8v;
typedef __attribute__((ext_vector_type(4))) unsigned int uint4v;

#define S_LEN 2048
#define DMODEL 1024
#define NHEAD 16
#define DHEAD 64
#define BATCH 4
#define NEGBIG (-1.0e30f)
#define LOG2E 1.4426950408889634f

__device__ __forceinline__ unsigned short f2bf(float f) {
  unsigned int u = __builtin_bit_cast(unsigned int, f);
  u += 0x7fffu + ((u >> 16) & 1u);
  return (unsigned short)(u >> 16);
}

// compiler-sanctioned packed f32x2 -> bf16x2 (lo -> bits[15:0])
__device__ __forceinline__ unsigned int pk2bf(float lo, float hi) {
  __hip_bfloat162 t = __float22bfloat162_rn(make_float2(lo, hi));
  unsigned int r;
  __builtin_memcpy(&r, &t, 4);
  return r;
}

__device__ __forceinline__ void gload16(const void* src, void* lds_dst) {
  __builtin_amdgcn_global_load_lds(
      (const __attribute__((address_space(1))) unsigned int*)src,
      (__attribute__((address_space(3))) unsigned int*)lds_dst, 16, 0, 0);
}

// ---------------- fp32 -> bf16 conversion (weights only) ----------------
__global__ __launch_bounds__(256) void cvt4_kernel(
    const float* __restrict__ i0, const float* __restrict__ i1,
    const float* __restrict__ i2, const float* __restrict__ i3,
    unsigned short* __restrict__ o0, unsigned short* __restrict__ o1,
    unsigned short* __restrict__ o2, unsigned short* __restrict__ o3, int n) {
  const float* in = (blockIdx.y == 0) ? i0 : (blockIdx.y == 1) ? i1 : (blockIdx.y == 2) ? i2 : i3;
  unsigned short* out = (blockIdx.y == 0) ? o0 : (blockIdx.y == 1) ? o1 : (blockIdx.y == 2) ? o2 : o3;
  int idx = blockIdx.x * blockDim.x + threadIdx.x;
  int stride = gridDim.x * blockDim.x;
  for (int j = idx * 8; j < n; j += stride * 8) {
    float4 a = *(const float4*)(in + j);
    float4 b = *(const float4*)(in + j + 4);
    ushort8v r;
    r[0] = f2bf(a.x); r[1] = f2bf(a.y); r[2] = f2bf(a.z); r[3] = f2bf(a.w);
    r[4] = f2bf(b.x); r[5] = f2bf(b.y); r[6] = f2bf(b.z); r[7] = f2bf(b.w);
    *(ushort8v*)(out + j) = r;
  }
}

// ------------- fused QKV GEMM: C = (A_f32[M][K] * W_bf16[N][K]^T + b) * osc -
// A read as fp32 directly, converted in-staging; prefetch issued AFTER the
// stage barrier so HBM latency hides under the MFMA phase.
__global__ __launch_bounds__(256) void qkv_gemm_kernel(
    const float* __restrict__ Aq, const float* __restrict__ Ak, const float* __restrict__ Av,
    const unsigned short* __restrict__ Wq, const unsigned short* __restrict__ Wk,
    const unsigned short* __restrict__ Wv,
    const float* __restrict__ bq, const float* __restrict__ bk, const float* __restrict__ bv,
    unsigned short* __restrict__ oq, unsigned short* __restrict__ ok,
    unsigned short* __restrict__ ov) {
  const int z = blockIdx.z;
  const float* A = (z == 0) ? Aq : (z == 1) ? Ak : Av;
  const unsigned short* W = (z == 0) ? Wq : (z == 1) ? Wk : Wv;
  const float* bias = (z == 0) ? bq : (z == 1) ? bk : bv;
  unsigned short* out = (z == 0) ? oq : (z == 1) ? ok : ov;
  const float oscale = (z == 0) ? 0.125f * LOG2E : 1.0f;
  const int N = DMODEL, K = DMODEL;

  __shared__ char lds[32768];  // A bf16 swizzled [0,16K) | B [16K,32K)
  const int tid = threadIdx.x;
  const int lane = tid & 63;
  const int wv = tid >> 6;
  const int wr = wv >> 1, wc = wv & 1;
  const int l16 = lane & 15, lg = lane >> 4;

  const int nbx = N >> 7;  // 8
  const int swz = (blockIdx.x & 7) * ((int)gridDim.x >> 3) + (blockIdx.x >> 3);
  const int tm = swz / nbx, tn = swz % nbx;

  const char* Wb = (const char*)W;

  // A staging: thread covers rows {tid>>3 + 32j}, 32B at col aslot*8
  const int arow[4] = {(tid >> 3), 32 + (tid >> 3), 64 + (tid >> 3), 96 + (tid >> 3)};
  const int aslot = tid & 7;

  float4 areg[4][2];
#pragma unroll
  for (int j = 0; j < 4; ++j) {
    const float* ap = A + (size_t)(tm * 128 + arow[j]) * K + aslot * 8;
    areg[j][0] = *(const float4*)ap;
    areg[j][1] = *(const float4*)(ap + 4);
  }

  f32x4 acc[4][4] = {};

  for (int k0 = 0; k0 < K; k0 += 64) {
    // B staging via global_load_lds (pre-swizzled source)
#pragma unroll
    for (int i = 0; i < 4; ++i) {
      int ch = wv * 4 + i;
      int r = ch * 8 + (lane >> 3);
      int cb = ((lane & 7) * 16) ^ ((r & 7) << 4);
      gload16(Wb + ((size_t)(tn * 128 + r) * K + k0) * 2 + cb, lds + 16384 + ch * 1024);
    }
    // A: convert regs -> bf16 (packed API) -> swizzled ds_write_b128
#pragma unroll
    for (int j = 0; j < 4; ++j) {
      uint4v w4;
      w4[0] = pk2bf(areg[j][0].x, areg[j][0].y);
      w4[1] = pk2bf(areg[j][0].z, areg[j][0].w);
      w4[2] = pk2bf(areg[j][1].x, areg[j][1].y);
      w4[3] = pk2bf(areg[j][1].z, areg[j][1].w);
      int r = arow[j];
      *(uint4v*)(lds + r * 128 + ((aslot * 16) ^ ((r & 7) << 4))) = w4;
    }
    __syncthreads();
    // prefetch next A k-slab AFTER the barrier: latency hides under MFMA
    if (k0 + 64 < K) {
#pragma unroll
      for (int j = 0; j < 4; ++j) {
        const float* ap = A + (size_t)(tm * 128 + arow[j]) * K + (k0 + 64) + aslot * 8;
        areg[j][0] = *(const float4*)ap;
        areg[j][1] = *(const float4*)(ap + 4);
      }
    }
#pragma unroll
    for (int ks = 0; ks < 2; ++ks) {
      const int cbase = (ks * 32 + lg * 8) * 2;
      short8 af[4], bfr[4];
#pragma unroll
      for (int m = 0; m < 4; ++m) {
        int r = wr * 64 + m * 16 + l16;
        af[m] = *(const short8*)(lds + r * 128 + (cbase ^ ((r & 7) << 4)));
      }
#pragma unroll
      for (int n = 0; n < 4; ++n) {
        int r = wc * 64 + n * 16 + l16;
        bfr[n] = *(const short8*)(lds + 16384 + r * 128 + (cbase ^ ((r & 7) << 4)));
      }
#pragma unroll
      for (int m = 0; m < 4; ++m)
#pragma unroll
        for (int n = 0; n < 4; ++n)
          acc[m][n] = __builtin_amdgcn_mfma_f32_16x16x32_bf16(af[m], bfr[n], acc[m][n], 0, 0, 0);
    }
    __syncthreads();
  }

  // epilogue
#pragma unroll
  for (int n = 0; n < 4; ++n) {
    int gn = tn * 128 + wc * 64 + n * 16 + l16;
    float bv2 = bias[gn];
    int h = gn >> 6, dh = gn & 63;
#pragma unroll
    for (int m = 0; m < 4; ++m) {
      int gm0 = tm * 128 + wr * 64 + m * 16 + lg * 4;
      f32x4 a = acc[m][n];
      if (z < 2) {
#pragma unroll
        for (int rr = 0; rr < 4; ++rr) {
          int gm = gm0 + rr;
          int b = gm >> 11, s = gm & 2047;
          out[(((size_t)b * NHEAD + h) * S_LEN + s) * DHEAD + dh] = f2bf((a[rr] + bv2) * oscale);
        }
      } else {
        int b = gm0 >> 11, s0 = gm0 & 2047;
        ushort4v pk;
        pk[0] = f2bf(a[0] + bv2); pk[1] = f2bf(a[1] + bv2);
        pk[2] = f2bf(a[2] + bv2); pk[3] = f2bf(a[3] + bv2);
        *(ushort4v*)(out + (((size_t)b * NHEAD + h) * DHEAD + dh) * S_LEN + s0) = pk;
      }
    }
  }
}

// ---------------- output-projection GEMM (bf16 A, fp32 out) ----------------
__global__ __launch_bounds__(256) void gemm_o_kernel(
    const unsigned short* __restrict__ A, const unsigned short* __restrict__ W,
    const float* __restrict__ bias, float* __restrict__ outp, int M, int N, int K) {
  __shared__ char lds[32768];
  const int tid = threadIdx.x;
  const int lane = tid & 63;
  const int wv = tid >> 6;
  const int wr = wv >> 1, wc = wv & 1;
  const int l16 = lane & 15, lg = lane >> 4;

  const int nbx = N >> 7;
  const int nwg = gridDim.x;
  const int swz = (blockIdx.x & 7) * (nwg >> 3) + (blockIdx.x >> 3);
  const int tm = swz / nbx, tn = swz % nbx;

  const char* Ab = (const char*)A;
  const char* Wb = (const char*)W;

  f32x4 acc[4][4] = {};

  for (int k0 = 0; k0 < K; k0 += 64) {
#pragma unroll
    for (int i = 0; i < 8; ++i) {
      int ch = wv * 8 + i;
      int chl = ch & 15;
      int r = chl * 8 + (lane >> 3);
      int cb = ((lane & 7) * 16) ^ ((r & 7) << 4);
      const char* src = (ch < 16)
          ? Ab + ((size_t)(tm * 128 + r) * K + k0) * 2 + cb
          : Wb + ((size_t)(tn * 128 + r) * K + k0) * 2 + cb;
      gload16(src, lds + ch * 1024);
    }
    __syncthreads();
#pragma unroll
    for (int ks = 0; ks < 2; ++ks) {
      const int cbase = (ks * 32 + lg * 8) * 2;
      short8 af[4], bfr[4];
#pragma unroll
      for (int m = 0; m < 4; ++m) {
        int r = wr * 64 + m * 16 + l16;
        af[m] = *(const short8*)(lds + r * 128 + (cbase ^ ((r & 7) << 4)));
      }
#pragma unroll
      for (int n = 0; n < 4; ++n) {
        int r = wc * 64 + n * 16 + l16;
        bfr[n] = *(const short8*)(lds + 16384 + r * 128 + (cbase ^ ((r & 7) << 4)));
      }
#pragma unroll
      for (int m = 0; m < 4; ++m)
#pragma unroll
        for (int n = 0; n < 4; ++n)
          acc[m][n] = __builtin_amdgcn_mfma_f32_16x16x32_bf16(af[m], bfr[n], acc[m][n], 0, 0, 0);
    }
    __syncthreads();
  }

#pragma unroll
  for (int n = 0; n < 4; ++n) {
    int gn = tn * 128 + wc * 64 + n * 16 + l16;
    float bv = bias[gn];
#pragma unroll
    for (int m = 0; m < 4; ++m) {
      int gm0 = tm * 128 + wr * 64 + m * 16 + lg * 4;
      f32x4 a = acc[m][n];
#pragma unroll
      for (int rr = 0; rr < 4; ++rr)
        outp[(size_t)(gm0 + rr) * N + gn] = a[rr] + bv;
    }
  }
}

// ---------------- causal flash attention, 4-wave 32x32 swapped-QK ----------
// qh (pre-scaled by log2e/8), kh: [B,H,S,DH] bf16   vt: [B,H,DH,S] bf16
// aout: [B,S,D] bf16.  exp2-domain softmax; defer-max threshold 8.
// QBLK=128 unpaired; grid(64 bh, 16 qb) heavy-first; dbuf LDS.
// Packed-API P-pack; proven shfl_xor exchange; T5 setprio around MFMA.
__global__ __launch_bounds__(256) void attn_kernel(
    const unsigned short* __restrict__ qh, const unsigned short* __restrict__ kh,
    const unsigned short* __restrict__ vt, unsigned short* __restrict__ aout) {
  __shared__ char lds[32768];  // 2 x (K 8KB | Vt 8KB)
  const int tid = threadIdx.x;
  const int lane = tid & 63;
  const int w = tid >> 6;     // 0..3
  const int l31 = lane & 31;
  const int l5 = lane >> 5;   // 0/1
  const int bh = blockIdx.x;
  const int b = bh >> 4, h = bh & 15;

  const char* kbase = (const char*)(kh + (size_t)bh * S_LEN * DHEAD);
  const char* vbase = (const char*)(vt + (size_t)bh * S_LEN * DHEAD);
  const unsigned short* qbase = qh + (size_t)bh * S_LEN * DHEAD;

  const int la = lane >> 3, lb = lane & 7;

  const int qb = 15 - (int)blockIdx.y;  // heavy q-blocks dispatched first
  const int q0 = qb * 128;
  const int wq0 = q0 + w * 32;
  const int qg = wq0 + l31;
  const int nt = qb * 2 + 2;

  short8 qf[4];
#pragma unroll
  for (int f = 0; f < 4; ++f)
    qf[f] = *(const short8*)(qbase + (size_t)qg * DHEAD + f * 16 + l5 * 8);

  f32x16 oa[2] = {};
  float mrun = NEGBIG, lr = 0.f;

  // prologue: stage tile 0 into buf0
#pragma unroll
  for (int i = 0; i < 2; ++i) {
    int ch = w * 2 + i;
    int r = ch * 8 + la;
    int cb = (lb * 16) ^ ((r & 7) << 4);
    gload16(kbase + (size_t)r * 128 + cb, lds + ch * 1024 + lane * 16);
    gload16(vbase + (size_t)r * 4096 + cb, lds + 8192 + ch * 1024 + lane * 16);
  }
  __syncthreads();
  int cur = 0;

  for (int t = 0; t < nt; ++t) {
    const int kv0 = t * 64;
    if (t + 1 < nt) {
      char* nb = lds + (cur ^ 1) * 16384;
#pragma unroll
      for (int i = 0; i < 2; ++i) {
        int ch = w * 2 + i;
        int r = ch * 8 + la;
        int cb = (lb * 16) ^ ((r & 7) << 4);
        gload16(kbase + (size_t)(kv0 + 64 + r) * 128 + cb, nb + ch * 1024 + lane * 16);
        gload16(vbase + (size_t)r * 4096 + (size_t)(kv0 + 64) * 2 + cb,
                nb + 8192 + ch * 1024 + lane * 16);
      }
    }
    if (kv0 <= wq0 + 31) {
      const char* ldk = lds + cur * 16384;
      const char* ldv = ldk + 8192;

      // QK^T swapped: sa = K * Q^T  -> lane holds S[k][q=l31], 32 k's
      f32x16 sa[2] = {};
      __builtin_amdgcn_s_setprio(1);
#pragma unroll
      for (int kb2 = 0; kb2 < 2; ++kb2) {
        const int kr = kb2 * 32 + l31;
        const char* rowp = ldk + kr * 128;
        const int sw = (kr & 7) << 4;
#pragma unroll
        for (int f = 0; f < 4; ++f) {
          short8 kf = *(const short8*)(rowp + ((f * 32 + l5 * 16) ^ sw));
          sa[kb2] = __builtin_amdgcn_mfma_f32_32x32x16_bf16(kf, qf[f], sa[kb2], 0, 0, 0);
        }
      }
      __builtin_amdgcn_s_setprio(0);

      // causal mask (finite sentinel)
      if (kv0 + 63 > wq0) {
#pragma unroll
        for (int kb2 = 0; kb2 < 2; ++kb2)
#pragma unroll
          for (int r = 0; r < 16; ++r) {
            int kgl = kv0 + kb2 * 32 + (r & 3) + 8 * (r >> 2) + 4 * l5;
            if (kgl > qg) sa[kb2][r] = NEGBIG;
          }
      }

      // tile max (in-lane + one cross-half exchange)
      float pm = sa[0][0];
#pragma unroll
      for (int kb2 = 0; kb2 < 2; ++kb2)
#pragma unroll
        for (int r = 0; r < 16; ++r) pm = fmaxf(pm, sa[kb2][r]);
      pm = fmaxf(pm, __shfl_xor(pm, 32));

      // defer-max: rescale only when max grows beyond 2^8
      if (!__all(pm <= mrun + 8.f)) {
        float mN = fmaxf(mrun, pm);
        float sc = __builtin_amdgcn_exp2f(mrun - mN);
        mrun = mN;
        lr *= sc;
        oa[0] *= sc;
        oa[1] *= sc;
      }

      // exp2 + packed-API bf16 pack + cross-half exchange -> P^T B-fragments
      float rs = 0.f;
      short8 pfrag[4];
#pragma unroll
      for (int kb2 = 0; kb2 < 2; ++kb2) {
        unsigned int wpk[8];
#pragma unroll
        for (int i = 0; i < 8; ++i) {
          float p0 = __builtin_amdgcn_exp2f(sa[kb2][2 * i] - mrun);
          float p1 = __builtin_amdgcn_exp2f(sa[kb2][2 * i + 1] - mrun);
          rs += p0 + p1;
          wpk[i] = pk2bf(p0, p1);
        }
#pragma unroll
        for (int g = 0; g < 2; ++g) {
          unsigned int o0 = l5 ? wpk[4 * g + 2] : wpk[4 * g];
          unsigned int o1 = l5 ? wpk[4 * g + 3] : wpk[4 * g + 1];
          unsigned int s0 = l5 ? wpk[4 * g] : wpk[4 * g + 2];
          unsigned int s1 = l5 ? wpk[4 * g + 1] : wpk[4 * g + 3];
          unsigned int r0 = (unsigned int)__shfl_xor((int)s0, 32);
          unsigned int r1 = (unsigned int)__shfl_xor((int)s1, 32);
          uint4v fw;
          fw[0] = l5 ? r0 : o0;
          fw[1] = l5 ? r1 : o1;
          fw[2] = l5 ? o0 : r0;
          fw[3] = l5 ? o1 : r1;
          pfrag[kb2 * 2 + g] = __builtin_bit_cast(short8, fw);
        }
      }
      rs += __shfl_xor(rs, 32);
      lr += rs;

      // PV swapped: O^T += V^T * P^T
      __builtin_amdgcn_s_setprio(1);
#pragma unroll
      for (int db = 0; db < 2; ++db) {
        const int vr = db * 32 + l31;
        const char* rowp = ldv + vr * 128;
        const int sw = (vr & 7) << 4;
#pragma unroll
        for (int f = 0; f < 4; ++f) {
          short8 vf = *(const short8*)(rowp + ((f * 32 + l5 * 16) ^ sw));
          oa[db] = __builtin_amdgcn_mfma_f32_32x32x16_bf16(vf, pfrag[f], oa[db], 0, 0, 0);
        }
      }
      __builtin_amdgcn_s_setprio(0);
    }
    __syncthreads();
    cur ^= 1;
  }

  // epilogue: O^T / l  -> aout[b, q, h*64+dh]
  float rl = 1.0f / lr;
  unsigned short* obase = aout + ((size_t)(b * S_LEN + qg)) * DMODEL + h * DHEAD;
#pragma unroll
  for (int db = 0; db < 2; ++db)
#pragma unroll
    for (int rq = 0; rq < 4; ++rq) {
      ushort4v pk;
#pragma unroll
      for (int j = 0; j < 4; ++j)
        pk[j] = f2bf(oa[db][rq * 4 + j] * rl);
      *(ushort4v*)(obase + db * 32 + 8 * rq + 4 * l5) = pk;
    }
}

extern "C" void kernel_launch(void* const* d_in, const int* in_sizes, int n_in,
                              void* d_out, int out_size, void* d_ws, size_t ws_size,
                              hipStream_t stream) {
  (void)in_sizes; (void)n_in; (void)out_size; (void)ws_size;
  const float* q  = (const float*)d_in[0];
  const float* k  = (const float*)d_in[1];
  const float* v  = (const float*)d_in[2];
  const float* wq = (const float*)d_in[4];
  const float* bq = (const float*)d_in[5];
  const float* wk = (const float*)d_in[6];
  const float* bk = (const float*)d_in[7];
  const float* wv = (const float*)d_in[8];
  const float* bv = (const float*)d_in[9];
  const float* wo = (const float*)d_in[10];
  const float* bo = (const float*)d_in[11];

  const size_t NACT = (size_t)BATCH * S_LEN * DMODEL;
  const size_t NW = (size_t)DMODEL * DMODEL;
  unsigned short* wqb = (unsigned short*)d_ws;
  unsigned short* wkb = wqb + NW;
  unsigned short* wvb = wkb + NW;
  unsigned short* wob = wvb + NW;
  unsigned short* qhb = wob + NW;
  unsigned short* khb = qhb + NACT;
  unsigned short* vtb = khb + NACT;
  unsigned short* aout = vtb + NACT;

  dim3 blk(256);
  cvt4_kernel<<<dim3(512, 4), blk, 0, stream>>>(wq, wk, wv, wo, wqb, wkb, wvb, wob, (int)NW);

  const int M = BATCH * S_LEN, N = DMODEL, K = DMODEL;
  const int grid = (M / 128) * (N / 128);  // 512
  qkv_gemm_kernel<<<dim3(grid, 1, 3), blk, 0, stream>>>(
      q, k, v, wqb, wkb, wvb, bq, bk, bv, qhb, khb, vtb);

  attn_kernel<<<dim3(64, 16), blk, 0, stream>>>(qhb, khb, vtb, aout);

  gemm_o_kernel<<<grid, blk, 0, stream>>>(aout, wob, bo, (float*)d_out, M, N, K);
}